// Round 6
// baseline (131.279 us; speedup 1.0000x reference)
//
#include <hip/hip_runtime.h>
#include <math.h>

#define C_CH 256
#define T_LEN 4096

// R19: wave-per-row drive. One wave owns one (b,c) row (64 lanes x 64 steps).
// - R18 post-mortem: per-wave fold grafted onto the block-coupled structure
//   regressed +3.9us (all waves paid fold latency, nothing removed). R15/R17/
//   R18 together show +-3us perturbations around the old structure; the
//   structure (2 blocks/CU x 4 generations, barriers, cross-wave scan) IS
//   the cost. Arithmetic floor of drive is ~3-4us VALU + ~5us HBM.
// - R19 structure: 256 drive blocks (+8 warm) = 1 generation/CU. Per wave:
//   per-wave fold (needed: own c), conv via rolling 4xfloat4 register
//   windows (2 loads/row/chunk prefetched under 216 FMAs of the previous
//   chunk), d[64] kept in regs, chunk S-scan -> wave scan with A^64 powers
//   -> replay for first crossing -> wave min-reduce. ZERO __syncthreads,
//   ZERO LDS in drive. d accumulation order bitwise-identical to R17
//   (Beff init; row0/1/2; k ascending). Scan decomposition changes
//   (A^64 tree vs A^8+A^512): Vin rounding differs, outputs are discrete
//   crossings (R17 already diverged from serial ref; absmax stayed 0.0).
// - Static indexing everywhere under full unroll (no scratch). VGPR ~190
//   under __launch_bounds__(512,2) cap 256.
// - XCD swizzle: jjband = ((i31&7)<<2)|(i31>>3); XCD x covers jj in
//   [32x,32x+32) per b -> ~4.3MB/XCD ~ L2, same locality as R13-R17.
// - Fusion remains dead (R3/R4/R12): kernel boundary is the only cheap sync.

__global__ __launch_bounds__(512, 2) void drive_scan_kernel(
    const float* __restrict__ x,
    const float* __restrict__ w3, const float* __restrict__ b3,
    const float* __restrict__ w5, const float* __restrict__ b5,
    const float* __restrict__ w9, const float* __restrict__ b9,
    const float* __restrict__ w_red, const float* __restrict__ b_red,
    const float* __restrict__ latency_scale,
    const float* __restrict__ og, const float* __restrict__ W1,
    const float* __restrict__ W2, float* __restrict__ ogT,
    float* __restrict__ sink,
    float* __restrict__ out_lat, float* __restrict__ out_act)
{
    const int blk = blockIdx.x;
    const int tid = threadIdx.x;

    if (blk < 8) {
        // --- og^T build (mlp reads it coalesced) + LLC warm of W1/W2,
        //     overlapped with the drive phase ---
        const int id = blk * 512 + tid;            // 0..4095
        const float4* og4 = (const float4*)og;     // 16384 float4 (256x256)
        const float4* W14 = (const float4*)W1;     // 8192 float4
        const float4* W24 = (const float4*)W2;     // 8192 float4
        const int jrow  = id >> 4;                 // og row this thread copies
        const int ibase = (id & 15) << 4;          // first col of its 16 elems
        #pragma unroll
        for (int v = 0; v < 4; ++v) {
            float4 q = og4[id * 4 + v];            // og[jrow][ibase+4v .. +3]
            const int i = ibase + v * 4;
            ogT[(i + 0) * 256 + jrow] = q.x;
            ogT[(i + 1) * 256 + jrow] = q.y;
            ogT[(i + 2) * 256 + jrow] = q.z;
            ogT[(i + 3) * 256 + jrow] = q.w;
        }
        float acc = 0.0f;
        #pragma unroll
        for (int v = 0; v < 2; ++v) {
            float4 q = W14[id + v * 4096]; acc += q.x + q.y + q.z + q.w;
        }
        #pragma unroll
        for (int v = 0; v < 2; ++v) {
            float4 q = W24[id + v * 4096]; acc += q.x + q.y + q.z + q.w;
        }
        sink[id] = acc;                            // keep W1/W2 loads alive
        return;
    }

    const int bb     = blk - 8;                    // 0..255
    const int b      = bb >> 5;                    // 0..7
    const int i31    = bb & 31;
    const int jjband = ((i31 & 7) << 2) | (i31 >> 3);   // bijective 0..31
    const int lane   = tid & 63;
    const int wv     = tid >> 6;                   // 0..7
    const int jj     = (jjband << 3) | wv;         // 0..255
    const int c      = (171 * jj) & 255;           // channel: 3*c = jj mod 256

    // --- per-wave weight fold: lanes 0..26 = 27 folded taps, lane 27 =
    //     folded bias. Same fmaf chains as R17/R18 -> same tap bits. ---
    float foldv = 0.0f;
    if (lane < 27) {
        const int r = lane / 9, k = lane - 9 * r;
        const int q0     = 18 * c + 6 * r;
        const int region = (q0 >= 1536) + (q0 >= 3072);
        const int p0     = q0 - region * 1536;
        const int K      = (region == 0) ? 3 : (region == 1 ? 5 : 9);
        const int off    = (9 - K) >> 1;
        const float* wP  = (region == 0) ? w3 : (region == 1 ? w5 : w9);
        const int kk     = k - off;
        if (kk >= 0 && kk < K) {
            const float* wr = w_red + c * 18 + 6 * r;
            #pragma unroll
            for (int j = 0; j < 6; ++j)
                foldv = fmaf(wr[j], wP[(p0 + j) * K + kk], foldv);
        }
    } else if (lane == 27) {
        float acc = b_red[c];
        #pragma unroll
        for (int r = 0; r < 3; ++r) {
            const int q0     = 18 * c + 6 * r;
            const int region = (q0 >= 1536) + (q0 >= 3072);
            const int p0     = q0 - region * 1536;
            const float* bP  = (region == 0) ? b3 : (region == 1 ? b5 : b9);
            const float* wr  = w_red + c * 18 + 6 * r;
            #pragma unroll
            for (int j = 0; j < 6; ++j) acc = fmaf(wr[j], bP[p0 + j], acc);
        }
        foldv = acc;
    }

    // broadcast taps once (readlane, compile-time lane indices)
    float tap[27];
    #pragma unroll
    for (int k = 0; k < 27; ++k) tap[k] = __shfl(foldv, k, 64);
    const float Beff = __shfl(foldv, 27, 64);

    // --- row base pointers; lane's float4 stream F[m] = P[m], m=0..17
    //     covers x[lane*64 - 4 .. lane*64 + 67] of the row ---
    const float4 Z4 = make_float4(0.f, 0.f, 0.f, 0.f);
    const float4* P0 = (const float4*)(x + ((size_t)b * C_CH + ((jj    ) & 255)) * T_LEN) + (lane * 16 - 1);
    const float4* P1 = (const float4*)(x + ((size_t)b * C_CH + ((jj + 1) & 255)) * T_LEN) + (lane * 16 - 1);
    const float4* P2 = (const float4*)(x + ((size_t)b * C_CH + ((jj + 2) & 255)) * T_LEN) + (lane * 16 - 1);

    // init windows F[0..3] per row; F[0] is zeros for lane 0 (t<0 pad) --
    // address-clamped so no OOB byte is touched.
    const int m0 = lane ? 0 : 1;
    float4 aP = P0[m0], bP = P1[m0], cP = P2[m0];
    if (lane == 0) { aP = Z4; bP = Z4; cP = Z4; }
    float4 aQ0 = P0[1], aQ1 = P0[2], aN = P0[3];
    float4 bQ0 = P1[1], bQ1 = P1[2], bN = P1[3];
    float4 cQ0 = P2[1], cQ1 = P2[2], cN = P2[3];

    float d[64];

    #pragma unroll
    for (int cc = 0; cc < 8; ++cc) {
        // prefetch next chunk's 2 float4 per row (F[2cc+4], F[2cc+5]);
        // F[17] is zeros for lane 63 (t>=4096 pad), address-clamped.
        float4 aX, aY, bX, bY, cX, cY;
        if (cc < 7) {
            const int m4 = 2 * cc + 4;
            aX = P0[m4]; bX = P1[m4]; cX = P2[m4];
            const int m5 = (cc == 6) ? ((lane == 63) ? 16 : 17) : (2 * cc + 5);
            aY = P0[m5]; bY = P1[m5]; cY = P2[m5];
            if (cc == 6 && lane == 63) { aY = Z4; bY = Z4; cY = Z4; }
        }

        // window arrays (static-indexed after unroll; pure register copies)
        const float w0[16] = { aP.x, aP.y, aP.z, aP.w, aQ0.x, aQ0.y, aQ0.z, aQ0.w,
                               aQ1.x, aQ1.y, aQ1.z, aQ1.w, aN.x, aN.y, aN.z, aN.w };
        const float w1[16] = { bP.x, bP.y, bP.z, bP.w, bQ0.x, bQ0.y, bQ0.z, bQ0.w,
                               bQ1.x, bQ1.y, bQ1.z, bQ1.w, bN.x, bN.y, bN.z, bN.w };
        const float w2[16] = { cP.x, cP.y, cP.z, cP.w, cQ0.x, cQ0.y, cQ0.z, cQ0.w,
                               cQ1.x, cQ1.y, cQ1.z, cQ1.w, cN.x, cN.y, cN.z, cN.w };

        // 27-tap FMA, order identical to R17: Beff init; row0, row1, row2;
        // k ascending -> bitwise-equal d values.
        #pragma unroll
        for (int tt = 0; tt < 8; ++tt) d[cc * 8 + tt] = Beff;
        #pragma unroll
        for (int k = 0; k < 9; ++k) {
            const float wk = tap[k];
            #pragma unroll
            for (int tt = 0; tt < 8; ++tt)
                d[cc * 8 + tt] = fmaf(wk, w0[tt + k], d[cc * 8 + tt]);
        }
        #pragma unroll
        for (int k = 0; k < 9; ++k) {
            const float wk = tap[9 + k];
            #pragma unroll
            for (int tt = 0; tt < 8; ++tt)
                d[cc * 8 + tt] = fmaf(wk, w1[tt + k], d[cc * 8 + tt]);
        }
        #pragma unroll
        for (int k = 0; k < 9; ++k) {
            const float wk = tap[18 + k];
            #pragma unroll
            for (int tt = 0; tt < 8; ++tt)
                d[cc * 8 + tt] = fmaf(wk, w2[tt + k], d[cc * 8 + tt]);
        }

        // shift windows
        if (cc < 7) {
            aP = aQ1; aQ0 = aN; aQ1 = aX; aN = aY;
            bP = bQ1; bQ0 = bN; bQ1 = bX; bN = bY;
            cP = cQ1; cQ0 = cN; cQ1 = cX; cN = cY;
        }
    }

    const float A   = (float)0.8187307530779818;          // exp(-1/5), fp32
    const float OMA = (float)(1.0 - 0.8187307530779818);  // matches ref rounding

    // --- lane-local scan: V after this lane's 64 steps from 0 ---
    float S = 0.0f;
    #pragma unroll
    for (int t = 0; t < 64; ++t) S = A * S + OMA * d[t];

    // --- wave-level weighted inclusive scan (per-lane decay A^64) ---
    // A^64 = e^-12.8; A^512 is denormal ~0; A^1024+ underflow to 0 (skip).
    const float Fp[4] = {
        (float)2.7607725720371943e-06,  // A^64
        (float)7.6218649302532563e-12,  // A^128
        (float)5.8092835977683129e-23,  // A^256
        (float)3.3744728758705166e-45   // A^512 (denormal ~ 0)
    };
    float cinc = S;
    #pragma unroll
    for (int s = 0; s < 4; ++s) {
        const int o = 1 << s;
        const float y = __shfl_up(cinc, o, 64);
        if (lane >= o) cinc = fmaf(Fp[s], y, cinc);
    }
    const float cprev = __shfl_up(cinc, 1, 64);
    const float Vin = lane ? cprev : 0.0f;

    // --- replay with true incoming V; first threshold crossing ---
    float V = Vin;
    int firstT = T_LEN;
    const int tb = lane << 6;
    #pragma unroll
    for (int t = 0; t < 64; ++t) {
        V = A * V + OMA * d[t];
        if (V >= 1.0f && firstT == T_LEN) firstT = tb + t;
    }

    // --- wave min-reduce; lane 0 writes ---
    #pragma unroll
    for (int o = 32; o > 0; o >>= 1)
        firstT = min(firstT, __shfl_xor(firstT, o, 64));
    if (lane == 0) {
        const float lat   = (float)firstT;                     // T if never fired
        const float scale = fmaxf(latency_scale[0], 0.001f);
        out_lat[(b << 8) + c] = lat;
        out_act[(b << 8) + c] = expf(-lat / scale);
    }
}

// ---------------------------------------------------------------------------
// K2: gated mix + 2-layer MLP + softplus/clip. One 512-thread block per
// batch row. Mix phase reads precomputed ogT (coalesced over j), single
// serial fmaf chain per g-half preserving the previous accumulation order
// bitwise. W1/W2 phases: split reductions, 1-2 latency rounds each.
// Weights LLC-warm from the drive-phase warm-up blocks.
// ---------------------------------------------------------------------------
__global__ __launch_bounds__(512) void mlp_kernel(
    const float* __restrict__ act,
    const float* __restrict__ ogT, const float* __restrict__ bias,
    const float* __restrict__ W1, const float* __restrict__ b1,
    const float* __restrict__ W2, const float* __restrict__ b2,
    float* __restrict__ out_pred)
{
    const int b = blockIdx.x;
    const int t = threadIdx.x;
    const int j = t & 255;             // output index for og/W2 phases
    const int g = t >> 8;              // reduction group 0/1

    __shared__ float sAct[256];
    __shared__ float sP[2][256];       // og partials
    __shared__ float sMix[256];
    __shared__ float sPH[4][128];      // W1 partials
    __shared__ float sH[128];
    __shared__ float sPR[2][256];      // W2 partials

    if (t < 256) sAct[t] = act[b * 256 + t];
    __syncthreads();

    // mixed[j] = bias[j] + sum_i act[i]*og[j,i]; group g covers
    // i in [g*128, g*128+128). ogT[i*256+j] is coalesced over j.
    float mix = 0.0f;
    {
        const float* col = ogT + (size_t)(g * 128) * 256 + j;
        const float* a   = sAct + g * 128;
        #pragma unroll 16
        for (int ii = 0; ii < 128; ++ii)
            mix = fmaf(a[ii], col[ii * 256], mix);
    }
    sP[g][j] = mix;
    __syncthreads();
    if (t < 256) sMix[t] = bias[t] + sP[0][t] + sP[1][t];
    __syncthreads();

    // h[j1] = relu(b1 + sum_i mixed[i]*W1[i,j1]); 4 partials per j1, each a
    // fully-unrolled 64-load round. W1 (256,128) row-major: coalesced.
    {
        const int j1  = t & 127;
        const int seg = t >> 7;        // 0..3
        float h = 0.0f;
        #pragma unroll
        for (int ii = 0; ii < 64; ++ii) {
            const int i = seg * 64 + ii;
            h = fmaf(sMix[i], W1[i * 128 + j1], h);
        }
        sPH[seg][j1] = h;
    }
    __syncthreads();
    if (t < 128)
        sH[t] = fmaxf(b1[t] + ((sPH[0][t] + sPH[1][t]) + (sPH[2][t] + sPH[3][t])), 0.0f);
    __syncthreads();

    // raw[j] = b2[j] + sum_k h[k]*W2[k,j]; 2 partials per j, 64-load rounds.
    {
        float raw = 0.0f;
        #pragma unroll
        for (int kk = 0; kk < 64; ++kk) {
            const int k = g * 64 + kk;
            raw = fmaf(sH[k], W2[k * 256 + j], raw);
        }
        sPR[g][j] = raw;
    }
    __syncthreads();
    if (t < 256) {
        const float r  = b2[t] + sPR[0][t] + sPR[1][t];
        const float sp = fmaxf(r, 0.0f) + log1pf(expf(-fabsf(r)));
        out_pred[b * 256 + t] = fminf(fmaxf(sp, 0.0f), 4096.0f);
    }
}

// ---------------------------------------------------------------------------
extern "C" void kernel_launch(void* const* d_in, const int* in_sizes, int n_in,
                              void* d_out, int out_size, void* d_ws, size_t ws_size,
                              hipStream_t stream) {
    const float* x    = (const float*)d_in[0];
    const float* w3   = (const float*)d_in[1];
    const float* b3   = (const float*)d_in[2];
    const float* w5   = (const float*)d_in[3];
    const float* b5   = (const float*)d_in[4];
    const float* w9   = (const float*)d_in[5];
    const float* b9   = (const float*)d_in[6];
    const float* wred = (const float*)d_in[7];
    const float* bred = (const float*)d_in[8];
    const float* ls   = (const float*)d_in[9];
    const float* og   = (const float*)d_in[10];
    const float* bias = (const float*)d_in[11];
    const float* W1   = (const float*)d_in[12];
    const float* b1   = (const float*)d_in[13];
    const float* W2   = (const float*)d_in[14];
    const float* b2   = (const float*)d_in[15];

    float* ogT      = (float*)d_ws;           // 65536 floats (256KB)
    float* sink     = (float*)d_ws + 65536;   // prefetch sink (4096 floats)
    float* out      = (float*)d_out;
    float* out_pred = out;              // (8,256)
    float* out_lat  = out + 2048;       // (8,256)
    float* out_act  = out + 4096;       // (8,256)

    drive_scan_kernel<<<264, 512, 0, stream>>>(
        x, w3, b3, w5, b5, w9, b9, wred, bred, ls,
        og, W1, W2, ogT, sink, out_lat, out_act);
    mlp_kernel<<<8, 512, 0, stream>>>(out_act, ogT, bias, W1, b1, W2, b2, out_pred);
}

// Round 7
// 118.457 us; speedup vs baseline: 1.1082x; 1.1082x over previous
//
#include <hip/hip_runtime.h>
#include <math.h>

#define C_CH 256
#define T_LEN 4096

// R20 = R17 reverted verbatim (best verified: 119.7us, absmax 0.0).
// - R18 (per-wave fold graft): +3.9us. R19 (wave-per-row): +11.6us --
//   long dependent chains (64-step scan + 128-op replay) at 2 waves/SIMD
//   + ~150 live VGPRs lost far more than the removed barriers gained.
// - R17 structure is the measured optimum: lane-per-8-steps (short chains),
//   single up-front load round, spill-free at (512,4), block-scan coupling
//   costs only ~3us total.
// - Session budget arithmetic: 122us window ~= 43us ws re-poison fill
//   (harness) + ~25-40us launch gaps/reset memsets (harness) + drive
//   (~25-35us) + mlp (~8-12us). Structural rewrites of drive both
//   regressed; remaining controllable margin is noise-level.
// - Fusion remains dead (R3/R4/R12): cross-XCD producer->consumer costs
//   60-100us; kernel boundary is the only cheap sync.

#define LOAD_ROW(xa, r) do {                                                  \
    const int src_ = (jj + (r)) & 255;                                        \
    const float4* p_ = (const float4*)(x + ((size_t)b * C_CH + src_) * T_LEN + t0); \
    float4 qm_ = tid ? p_[-1] : p_[0];                                        \
    float4 q0_ = p_[0], q1_ = p_[1];                                          \
    float4 q2_ = (tid < 511) ? p_[2] : p_[1];                                 \
    if (tid == 0)   qm_ = make_float4(0.f, 0.f, 0.f, 0.f);                    \
    if (tid == 511) q2_ = make_float4(0.f, 0.f, 0.f, 0.f);                    \
    xa[0]  = qm_.x; xa[1]  = qm_.y; xa[2]  = qm_.z; xa[3]  = qm_.w;           \
    xa[4]  = q0_.x; xa[5]  = q0_.y; xa[6]  = q0_.z; xa[7]  = q0_.w;           \
    xa[8]  = q1_.x; xa[9]  = q1_.y; xa[10] = q1_.z; xa[11] = q1_.w;           \
    xa[12] = q2_.x; xa[13] = q2_.y; xa[14] = q2_.z; xa[15] = q2_.w;           \
} while (0)

__global__ __launch_bounds__(512, 4) void drive_scan_kernel(
    const float* __restrict__ x,
    const float* __restrict__ w3, const float* __restrict__ b3,
    const float* __restrict__ w5, const float* __restrict__ b5,
    const float* __restrict__ w9, const float* __restrict__ b9,
    const float* __restrict__ w_red, const float* __restrict__ b_red,
    const float* __restrict__ latency_scale,
    const float* __restrict__ og, const float* __restrict__ W1,
    const float* __restrict__ W2, float* __restrict__ ogT,
    float* __restrict__ sink,
    float* __restrict__ out_lat, float* __restrict__ out_act)
{
    const int blk = blockIdx.x;
    const int tid = threadIdx.x;

    if (blk < 8) {
        // --- og^T build (mlp reads it coalesced) + LLC warm of W1/W2,
        //     overlapped with the drive phase head ---
        const int id = blk * 512 + tid;            // 0..4095
        const float4* og4 = (const float4*)og;     // 16384 float4 (256x256)
        const float4* W14 = (const float4*)W1;     // 8192 float4
        const float4* W24 = (const float4*)W2;     // 8192 float4
        const int jrow  = id >> 4;                 // og row this thread copies
        const int ibase = (id & 15) << 4;          // first col of its 16 elems
        #pragma unroll
        for (int v = 0; v < 4; ++v) {
            float4 q = og4[id * 4 + v];            // og[jrow][ibase+4v .. +3]
            const int i = ibase + v * 4;
            ogT[(i + 0) * 256 + jrow] = q.x;
            ogT[(i + 1) * 256 + jrow] = q.y;
            ogT[(i + 2) * 256 + jrow] = q.z;
            ogT[(i + 3) * 256 + jrow] = q.w;
        }
        float acc = 0.0f;
        #pragma unroll
        for (int v = 0; v < 2; ++v) {
            float4 q = W14[id + v * 4096]; acc += q.x + q.y + q.z + q.w;
        }
        #pragma unroll
        for (int v = 0; v < 2; ++v) {
            float4 q = W24[id + v * 4096]; acc += q.x + q.y + q.z + q.w;
        }
        sink[id] = acc;                            // keep W1/W2 loads alive
        return;
    }

    const int bb   = blk - 8;
    const int b    = bb >> 8;
    const int i255 = bb & 255;
    // XCD-contiguous band index (dispatch round-robins blk % 8 across XCDs)
    const int jj   = ((i255 & 7) << 5) | (i255 >> 3);
    const int c    = (171 * jj) & 255;             // channel: 3*c = jj mod 256
    const int lane = tid & 63;
    const int wv   = tid >> 6;                     // 0..7

    __shared__ float sWF[28];                      // 27 folded taps + Beff
    __shared__ float sWaveTot[8];
    __shared__ float sCarry[8];
    __shared__ int   sMin[8];

    const int t0 = tid << 3;                       // this thread's 8 steps

    // --- parallel in-block weight fold FIRST (threads 0..27): its dependent
    //     scalar-load chain feeds the barrier, so it must not queue behind
    //     the bulk loads (vmcnt drains FIFO) ---
    if (tid < 27) {
        const int r = tid / 9, k = tid - 9 * r;
        const int q0     = 18 * c + 6 * r;
        const int region = (q0 >= 1536) + (q0 >= 3072);
        const int p0     = q0 - region * 1536;
        const int K      = (region == 0) ? 3 : (region == 1 ? 5 : 9);
        const int off    = (9 - K) >> 1;
        const float* wP  = (region == 0) ? w3 : (region == 1 ? w5 : w9);
        const int kk     = k - off;
        float w = 0.0f;
        if (kk >= 0 && kk < K) {
            const float* wr = w_red + c * 18 + 6 * r;
            #pragma unroll
            for (int j = 0; j < 6; ++j)
                w = fmaf(wr[j], wP[(p0 + j) * K + kk], w);
        }
        sWF[tid] = w;
    } else if (tid == 27) {
        float acc = b_red[c];
        #pragma unroll
        for (int r = 0; r < 3; ++r) {
            const int q0     = 18 * c + 6 * r;
            const int region = (q0 >= 1536) + (q0 >= 3072);
            const int p0     = q0 - region * 1536;
            const float* bP  = (region == 0) ? b3 : (region == 1 ? b5 : b9);
            const float* wr  = w_red + c * 18 + 6 * r;
            #pragma unroll
            for (int j = 0; j < 6; ++j) acc = fmaf(wr[j], bP[p0 + j], acc);
        }
        sWF[27] = acc;
    }

    // --- issue ALL conv loads: 3 rows x 4 aligned float4 ---
    float xa0[16], xa1[16], xa2[16];
    LOAD_ROW(xa0, 0);
    LOAD_ROW(xa1, 1);
    LOAD_ROW(xa2, 2);

    __syncthreads();   // publishes sWF; single vmcnt drain for all loads

    // --- 27-tap FMA into d[8]; same order as R14/R15 -> bitwise equal ---
    float d[8];
    {
        const float Beff = sWF[27];
        #pragma unroll
        for (int tt = 0; tt < 8; ++tt) d[tt] = Beff;
    }
    #pragma unroll
    for (int k = 0; k < 9; ++k) {
        const float wk = sWF[k];
        #pragma unroll
        for (int tt = 0; tt < 8; ++tt)
            d[tt] = fmaf(wk, xa0[tt + k], d[tt]);
    }
    #pragma unroll
    for (int k = 0; k < 9; ++k) {
        const float wk = sWF[9 + k];
        #pragma unroll
        for (int tt = 0; tt < 8; ++tt)
            d[tt] = fmaf(wk, xa1[tt + k], d[tt]);
    }
    #pragma unroll
    for (int k = 0; k < 9; ++k) {
        const float wk = sWF[18 + k];
        #pragma unroll
        for (int tt = 0; tt < 8; ++tt)
            d[tt] = fmaf(wk, xa2[tt + k], d[tt]);
    }

    const float A   = (float)0.8187307530779818;          // exp(-1/5), fp32
    const float OMA = (float)(1.0 - 0.8187307530779818);  // matches ref rounding

    // --- chunk-local scan: V after 8 steps from 0 ---
    float S = 0.0f;
    #pragma unroll
    for (int tt = 0; tt < 8; ++tt) S = A * S + OMA * d[tt];

    // --- wave-level weighted inclusive scan (per-chunk decay A^8) ---
    const float Fp[6] = {
        (float)2.0189651799465541e-01,  // A^8   = e^-1.6
        (float)4.0762203978366215e-02,  // A^16
        (float)1.6615572731739337e-03,  // A^32
        (float)2.7607725720371943e-06,  // A^64
        (float)7.6218649302532563e-12,  // A^128
        (float)5.8092835977683129e-23   // A^256
    };
    float cinc = S;
    #pragma unroll
    for (int s = 0; s < 6; ++s) {
        const int o = 1 << s;
        const float y = __shfl_up(cinc, o, 64);
        if (lane >= o) cinc = fmaf(Fp[s], y, cinc);
    }
    if (lane == 63) sWaveTot[wv] = cinc;
    __syncthreads();
    if (tid == 0) {
        // cross-wave decay A^512 ~ 3.4e-45 (denormal ~ 0)
        const float A512 = 3.3744728758705166e-45f;
        float g = 0.0f;
        #pragma unroll
        for (int w = 0; w < 8; ++w) { sCarry[w] = g; g = sWaveTot[w] + A512 * g; }
    }
    __syncthreads();
    const float cprev = __shfl_up(cinc, 1, 64);
    const float Vin = (lane ? cprev : 0.0f)
                    + expf(-1.6f * (float)lane) * sCarry[wv];

    // --- replay chunk with true incoming V; first threshold crossing ---
    float V = Vin;
    int firstT = T_LEN;
    #pragma unroll
    for (int tt = 0; tt < 8; ++tt) {
        V = A * V + OMA * d[tt];
        if (V >= 1.0f && firstT == T_LEN) firstT = t0 + tt;
    }

    // --- block min-reduce ---
    #pragma unroll
    for (int o = 32; o > 0; o >>= 1)
        firstT = min(firstT, __shfl_xor(firstT, o, 64));
    if (lane == 0) sMin[wv] = firstT;
    __syncthreads();
    if (tid == 0) {
        int f = sMin[0];
        #pragma unroll
        for (int w = 1; w < 8; ++w) f = min(f, sMin[w]);
        const float lat   = (float)f;                          // T if never fired
        const float scale = fmaxf(latency_scale[0], 0.001f);
        out_lat[(b << 8) + c] = lat;
        out_act[(b << 8) + c] = expf(-lat / scale);
    }
}

// ---------------------------------------------------------------------------
// K2: gated mix + 2-layer MLP + softplus/clip. One 512-thread block per
// batch row. Mix phase reads precomputed ogT (coalesced over j), single
// serial fmaf chain per g-half preserving the previous accumulation order
// bitwise. W1/W2 phases: split reductions, 1-2 latency rounds each.
// Weights LLC-warm from the drive-phase warm-up blocks.
// ---------------------------------------------------------------------------
__global__ __launch_bounds__(512) void mlp_kernel(
    const float* __restrict__ act,
    const float* __restrict__ ogT, const float* __restrict__ bias,
    const float* __restrict__ W1, const float* __restrict__ b1,
    const float* __restrict__ W2, const float* __restrict__ b2,
    float* __restrict__ out_pred)
{
    const int b = blockIdx.x;
    const int t = threadIdx.x;
    const int j = t & 255;             // output index for og/W2 phases
    const int g = t >> 8;              // reduction group 0/1

    __shared__ float sAct[256];
    __shared__ float sP[2][256];       // og partials
    __shared__ float sMix[256];
    __shared__ float sPH[4][128];      // W1 partials
    __shared__ float sH[128];
    __shared__ float sPR[2][256];      // W2 partials

    if (t < 256) sAct[t] = act[b * 256 + t];
    __syncthreads();

    // mixed[j] = bias[j] + sum_i act[i]*og[j,i]; group g covers
    // i in [g*128, g*128+128). ogT[i*256+j] is coalesced over j.
    float mix = 0.0f;
    {
        const float* col = ogT + (size_t)(g * 128) * 256 + j;
        const float* a   = sAct + g * 128;
        #pragma unroll 16
        for (int ii = 0; ii < 128; ++ii)
            mix = fmaf(a[ii], col[ii * 256], mix);
    }
    sP[g][j] = mix;
    __syncthreads();
    if (t < 256) sMix[t] = bias[t] + sP[0][t] + sP[1][t];
    __syncthreads();

    // h[j1] = relu(b1 + sum_i mixed[i]*W1[i,j1]); 4 partials per j1, each a
    // fully-unrolled 64-load round. W1 (256,128) row-major: coalesced.
    {
        const int j1  = t & 127;
        const int seg = t >> 7;        // 0..3
        float h = 0.0f;
        #pragma unroll
        for (int ii = 0; ii < 64; ++ii) {
            const int i = seg * 64 + ii;
            h = fmaf(sMix[i], W1[i * 128 + j1], h);
        }
        sPH[seg][j1] = h;
    }
    __syncthreads();
    if (t < 128)
        sH[t] = fmaxf(b1[t] + ((sPH[0][t] + sPH[1][t]) + (sPH[2][t] + sPH[3][t])), 0.0f);
    __syncthreads();

    // raw[j] = b2[j] + sum_k h[k]*W2[k,j]; 2 partials per j, 64-load rounds.
    {
        float raw = 0.0f;
        #pragma unroll
        for (int kk = 0; kk < 64; ++kk) {
            const int k = g * 64 + kk;
            raw = fmaf(sH[k], W2[k * 256 + j], raw);
        }
        sPR[g][j] = raw;
    }
    __syncthreads();
    if (t < 256) {
        const float r  = b2[t] + sPR[0][t] + sPR[1][t];
        const float sp = fmaxf(r, 0.0f) + log1pf(expf(-fabsf(r)));
        out_pred[b * 256 + t] = fminf(fmaxf(sp, 0.0f), 4096.0f);
    }
}

// ---------------------------------------------------------------------------
extern "C" void kernel_launch(void* const* d_in, const int* in_sizes, int n_in,
                              void* d_out, int out_size, void* d_ws, size_t ws_size,
                              hipStream_t stream) {
    const float* x    = (const float*)d_in[0];
    const float* w3   = (const float*)d_in[1];
    const float* b3   = (const float*)d_in[2];
    const float* w5   = (const float*)d_in[3];
    const float* b5   = (const float*)d_in[4];
    const float* w9   = (const float*)d_in[5];
    const float* b9   = (const float*)d_in[6];
    const float* wred = (const float*)d_in[7];
    const float* bred = (const float*)d_in[8];
    const float* ls   = (const float*)d_in[9];
    const float* og   = (const float*)d_in[10];
    const float* bias = (const float*)d_in[11];
    const float* W1   = (const float*)d_in[12];
    const float* b1   = (const float*)d_in[13];
    const float* W2   = (const float*)d_in[14];
    const float* b2   = (const float*)d_in[15];

    float* ogT      = (float*)d_ws;           // 65536 floats (256KB)
    float* sink     = (float*)d_ws + 65536;   // prefetch sink (4096 floats)
    float* out      = (float*)d_out;
    float* out_pred = out;              // (8,256)
    float* out_lat  = out + 2048;       // (8,256)
    float* out_act  = out + 4096;       // (8,256)

    drive_scan_kernel<<<2056, 512, 0, stream>>>(
        x, w3, b3, w5, b5, w9, b9, wred, bred, ls,
        og, W1, W2, ogT, sink, out_lat, out_act);
    mlp_kernel<<<8, 512, 0, stream>>>(out_act, ogT, bias, W1, b1, W2, b2, out_pred);
}